// Round 1
// baseline (218.396 us; speedup 1.0000x reference)
//
#include <hip/hip_runtime.h>
#include <math.h>

#define E_LEN 512
#define M_FEA 8
#define C_CLS 14
#define BATCH 8192
#define S_PER_BLOCK 4

// ---- DPP helpers (VALU-pipe cross-lane; avoids LDS-pipe shuffles) ----
template<int CTRL>
__device__ __forceinline__ float dpp_mov_f(float v) {
  return __int_as_float(__builtin_amdgcn_update_dpp(
      0, __float_as_int(v), CTRL, 0xF, 0xF, false));
}
// full sum across a row of 16 lanes (ror 8,4,2,1)
__device__ __forceinline__ float sum16(float v) {
  v += dpp_mov_f<0x128>(v);
  v += dpp_mov_f<0x124>(v);
  v += dpp_mov_f<0x122>(v);
  v += dpp_mov_f<0x121>(v);
  return v;
}
// partial: each lane ends with sum of lanes {i, i+4, i+8, i+12} of its row16
__device__ __forceinline__ float sum4_16(float v) {
  v += dpp_mov_f<0x128>(v);
  v += dpp_mov_f<0x124>(v);
  return v;
}
// max across aligned groups of 8 lanes (quad_perm xor1, xor2, half-mirror)
__device__ __forceinline__ float max8(float v) {
  v = fmaxf(v, dpp_mov_f<0xB1>(v));
  v = fmaxf(v, dpp_mov_f<0x4E>(v));
  v = fmaxf(v, dpp_mov_f<0x141>(v));
  return v;
}
__device__ __forceinline__ float softplus_f(float v) {
  return fmaxf(v, 0.f) + __logf(1.f + __expf(-fabsf(v)));
}

// ---- prep: pack w into the LDS image layout, compute Gram G = w^T w,
//      and zero the output accumulator ----
// ws layout (floats): [0..7167] packed w:
//   for half h in {0,1}: 3 paired rows [512][2] at h*3584 + p*1024,
//   then 1 single row [512] at h*3584 + 3072.
// [7168..7363]: G[14][14]
__global__ void MID_LOSS_prep(const float* __restrict__ w,
                              float* __restrict__ wsf,
                              float* __restrict__ out) {
  __shared__ float wc[E_LEN];
  __shared__ float red[16];
  const int tid = threadIdx.x;
  const int c = blockIdx.x;

  for (int i = tid; i < E_LEN; i += 256) wc[i] = w[i * C_CLS + c];
  __syncthreads();

  const int h = (c >= 7) ? 1 : 0;
  const int ci = c - h * 7;
  for (int i = tid; i < E_LEN; i += 256) {
    int pos = (ci < 6) ? (h * 3584 + (ci >> 1) * 1024 + 2 * i + (ci & 1))
                       : (h * 3584 + 3072 + i);
    wsf[pos] = wc[i];
  }

  for (int c2 = 0; c2 < C_CLS; ++c2) {
    float part = 0.f;
    for (int i = tid; i < E_LEN; i += 256) part = fmaf(wc[i], w[i * C_CLS + c2], part);
    part = sum16(part);
    if ((tid & 15) == 0) red[tid >> 4] = part;
    __syncthreads();
    if (tid == 0) {
      float s = 0.f;
      for (int r = 0; r < 16; ++r) s += red[r];
      wsf[7168 + c * C_CLS + c2] = s;
    }
    __syncthreads();
  }
  if (c == 0 && tid == 0) out[0] = 0.f;
}

// ---- main: 1 block = 4 samples; 4 waves = (c-half, e-half) ----
__global__ __launch_bounds__(256, 3)
void MID_LOSS_main(const float* __restrict__ x, const int* __restrict__ y,
                   const float* __restrict__ wsf, float* __restrict__ out) {
  __shared__ float w_lds[7168];        // packed w (28 KB)
  __shared__ float G_lds[196];
  __shared__ float P_lds[C_CLS];
  __shared__ float dotc_lds[C_CLS];
  __shared__ float scratch[14 * 264];  // dot partials: [c][32 part][8 m], padded
  __shared__ float pair_scr[16];
  __shared__ float g_scr[16];
  __shared__ float l1_scr[8];

  const int tid = threadIdx.x;
  const int lane = tid & 63;
  const int wid = tid >> 6;
  const int ch = wid & 1;   // c-half: 0 -> classes 0..6, 1 -> 7..13
  const int eh = wid >> 1;  // e-half: 0 -> e 0..255, 1 -> 256..511

  // prologue: stage packed w + G into LDS
#pragma unroll
  for (int i = 0; i < 7; ++i) {
    int idx = tid + i * 256;
    ((float4*)w_lds)[idx] = ((const float4*)wsf)[idx];
  }
  if (tid < 196) G_lds[tid] = wsf[7168 + tid];

  float block_loss = 0.f;

  for (int s = 0; s < S_PER_BLOCK; ++s) {
    const int b = blockIdx.x * S_PER_BLOCK + s;
    const float* xrow = x + (size_t)b * (E_LEN * M_FEA);

    __syncthreads();  // bar A: prologue ready / previous sample fully consumed
    if (tid < C_CLS) P_lds[tid] = (y[b * C_CLS + tid] == 1) ? 1.f : 0.f;

    // ---- phase 1: dot products + fused M-variance (sig2 -> l1) ----
    float U[4][8];
#pragma unroll
    for (int j = 0; j < 4; ++j) {
      const int e = eh * 256 + j * 64 + lane;
      *(float4*)&U[j][0] = *(const float4*)(xrow + e * 8);
      *(float4*)&U[j][4] = *(const float4*)(xrow + e * 8 + 4);
    }
    float acc[7][8];
#pragma unroll
    for (int ci = 0; ci < 7; ++ci)
#pragma unroll
      for (int m = 0; m < 8; ++m) acc[ci][m] = 0.f;
    float l1 = 0.f;
    const float* wb = w_lds + ch * 3584;
#pragma unroll
    for (int j = 0; j < 4; ++j) {
      const int e = eh * 256 + j * 64 + lane;
#pragma unroll
      for (int cp = 0; cp < 3; ++cp) {
        const float2 w2 = *(const float2*)(wb + cp * 1024 + 2 * e);
#pragma unroll
        for (int m = 0; m < 8; ++m) {
          acc[2 * cp][m]     = fmaf(U[j][m], w2.x, acc[2 * cp][m]);
          acc[2 * cp + 1][m] = fmaf(U[j][m], w2.y, acc[2 * cp + 1][m]);
        }
      }
      const float w1 = wb[3072 + e];
#pragma unroll
      for (int m = 0; m < 8; ++m) acc[6][m] = fmaf(U[j][m], w1, acc[6][m]);

      if (ch == 0) {  // each e visited exactly once across the two ch==0 waves
        float s1 = 0.f, s2 = 0.f;
#pragma unroll
        for (int m = 0; m < 8; ++m) {
          s1 += U[j][m];
          s2 = fmaf(U[j][m], U[j][m], s2);
        }
        const float sig = (s2 - s1 * s1 * 0.125f) * (1.f / 7.f);  // ddof=1
        l1 += fabsf(sig);
      }
    }
    // partial in-wave reduce (16 lanes -> 4 partials per row), then LDS scratch
#pragma unroll
    for (int ci = 0; ci < 7; ++ci)
#pragma unroll
      for (int m = 0; m < 8; ++m) acc[ci][m] = sum4_16(acc[ci][m]);
    if ((lane & 15) < 4) {
      const int part = eh * 16 + (lane >> 4) * 4 + (lane & 3);  // 0..31
#pragma unroll
      for (int ci = 0; ci < 7; ++ci) {
        const int c = ch * 7 + ci;
        *(float4*)(scratch + c * 264 + part * 8) =
            make_float4(acc[ci][0], acc[ci][1], acc[ci][2], acc[ci][3]);
        *(float4*)(scratch + c * 264 + part * 8 + 4) =
            make_float4(acc[ci][4], acc[ci][5], acc[ci][6], acc[ci][7]);
      }
    }
    if (ch == 0) {
      const float l1s = sum16(l1);
      if ((lane & 15) == 0) l1_scr[eh * 4 + (lane >> 4)] = l1s;
    }
    __syncthreads();  // bar B

    // ---- phase 2: finish dot reduction, max over m -> dotc[c] ----
    if (wid < 2) {  // 128 lanes, all active (DPP-safe); t>=112 duplicate c=13
      const int craw = tid >> 3;
      const int c = (craw > 13) ? 13 : craw;
      const int m = tid & 7;
      float dv = 0.f;
#pragma unroll
      for (int p = 0; p < 32; ++p) dv += scratch[c * 264 + p * 8 + m];
      dv = max8(dv);  // max over the 8 m-lanes of this group
      if ((tid & 7) == 0 && craw < 14) dotc_lds[c] = dv;
    }
    __syncthreads();  // bar C

    // ---- phase 3: 196 (p,n) pairs -> pair softplus sum + masked Gram sum ----
    {
      const int tt = (tid < 196) ? tid : 0;
      const int p = tt / 14;
      const int n = tt - p * 14;
      const float act = (tid < 196) ? 1.f : 0.f;
      const float Pp = P_lds[p];
      const float Pn = P_lds[n];
      const float v = dotc_lds[n] - dotc_lds[p];
      float aP = act * Pp * (1.f - Pn) * softplus_f(v);
      float aG = act * Pp * Pn * G_lds[tt];
      aP = sum16(aP);
      aG = sum16(aG);
      if ((lane & 15) == 0) {
        pair_scr[tid >> 4] = aP;
        g_scr[tid >> 4] = aG;
      }
    }
    __syncthreads();  // bar D

    // ---- phase 4: per-sample assembly (thread 0) ----
    if (tid == 0) {
      float S = 0.f, sumG = 0.f;
#pragma unroll
      for (int r = 0; r < 16; ++r) { S += pair_scr[r]; sumG += g_scr[r]; }
      float l1e = 0.f;
#pragma unroll
      for (int r = 0; r < 8; ++r) l1e += l1_scr[r];
      float npos = 0.f;
      for (int c = 0; c < C_CLS; ++c) npos += P_lds[c];
      const float nneg = (float)C_CLS - npos;
      float base;
      if (nneg > 0.f) {
        base = S / npos;
      } else {  // reference edge case (unreachable with this setup, kept for fidelity)
        float t = 0.f;
        for (int c = 0; c < C_CLS; ++c)
          if (P_lds[c] > 0.5f) t += softplus_f(-dotc_lds[c]);
        base = t / npos;
      }
      // diversity via Gram identity: sum_e ss = sum_{c in P} G[c][c] - sumG/npos
      float sumW2 = 0.f;
      for (int c = 0; c < C_CLS; ++c) sumW2 += P_lds[c] * G_lds[c * C_CLS + c];
      float tv = 0.f;
      if (npos > 1.5f) tv = (sumW2 - sumG / npos) / (npos - 1.f);
      // loss = 2*((1-beta)*(1+tv)*base + beta*l1), beta=0.3
      block_loss += 1.4f * (1.f + tv) * base + 0.6f * l1e;
    }
  }
  if (tid == 0) atomicAdd(out, block_loss * (1.f / (float)BATCH));
}

extern "C" void kernel_launch(void* const* d_in, const int* in_sizes, int n_in,
                              void* d_out, int out_size, void* d_ws, size_t ws_size,
                              hipStream_t stream) {
  const float* x = (const float*)d_in[0];
  const int* y = (const int*)d_in[1];
  const float* w = (const float*)d_in[2];
  float* out = (float*)d_out;
  float* wsf = (float*)d_ws;

  MID_LOSS_prep<<<C_CLS, 256, 0, stream>>>(w, wsf, out);
  MID_LOSS_main<<<BATCH / S_PER_BLOCK, 256, 0, stream>>>(x, y, wsf, out);
}

// Round 2
// 212.373 us; speedup vs baseline: 1.0284x; 1.0284x over previous
//
#include <hip/hip_runtime.h>
#include <math.h>

#define E_LEN 512
#define C_CLS 14
#define BATCH 8192
#define S_PER_BLOCK 4
#define NSLOTS 256

// ---- DPP helpers (VALU-pipe cross-lane; avoids LDS-pipe shuffles) ----
template<int CTRL>
__device__ __forceinline__ float dpp_mov_f(float v) {
  return __int_as_float(__builtin_amdgcn_update_dpp(
      0, __float_as_int(v), CTRL, 0xF, 0xF, false));
}
// full sum across a row of 16 lanes (ror 8,4,2,1)
__device__ __forceinline__ float sum16(float v) {
  v += dpp_mov_f<0x128>(v);
  v += dpp_mov_f<0x124>(v);
  v += dpp_mov_f<0x122>(v);
  v += dpp_mov_f<0x121>(v);
  return v;
}
// partial: lanes 0-3 of each row16 end with sum of {i, i+4, i+8, i+12}
__device__ __forceinline__ float sum4_16(float v) {
  v += dpp_mov_f<0x128>(v);
  v += dpp_mov_f<0x124>(v);
  return v;
}
// max across aligned groups of 8 lanes
__device__ __forceinline__ float max8(float v) {
  v = fmaxf(v, dpp_mov_f<0xB1>(v));
  v = fmaxf(v, dpp_mov_f<0x4E>(v));
  v = fmaxf(v, dpp_mov_f<0x141>(v));
  return v;
}
__device__ __forceinline__ float softplus_f(float v) {
  return fmaxf(v, 0.f) + __logf(1.f + __expf(-fabsf(v)));
}

// ---- prep (1 block): zero 256 slots, compute Gram G = w^T w into ws[256..451]
__global__ void MID_LOSS_prep(const float* __restrict__ w,
                              float* __restrict__ wsf) {
  __shared__ float wl[E_LEN * C_CLS];
  const int tid = threadIdx.x;
#pragma unroll
  for (int i = 0; i < 7; ++i)
    ((float4*)wl)[tid + i * 256] = ((const float4*)w)[tid + i * 256];
  wsf[tid] = 0.f;  // slots
  __syncthreads();
  if (tid < 196) {
    const int p = tid / 14, n = tid - p * 14;
    float g = 0.f;
    for (int e = 0; e < E_LEN; ++e)
      g = fmaf(wl[e * 14 + p], wl[e * 14 + n], g);
    wsf[NSLOTS + tid] = g;
  }
}

// ---- main: 1 block = 4 samples; 4 waves = (e-half, m-half); x read ONCE ----
__global__ __launch_bounds__(256, 3)
void MID_LOSS_main(const float* __restrict__ x, const int* __restrict__ y,
                   const float* __restrict__ w, const float* __restrict__ wsf,
                   float* __restrict__ slots) {
  __shared__ float wp_s[7 * 1024];      // [c-pair][e][2] float2-packed w (28 KB)
  __shared__ float scr[14 * 264];       // dot partials [c][part32][m8] (14.4 KB)
  __shared__ float var_s[E_LEN * 2];    // per-e (s1,s2) of the mh=1 half (4 KB)
  __shared__ float G_s[196];
  __shared__ float P_s[C_CLS];
  __shared__ float dot_s[C_CLS];
  __shared__ float pair_scr[16], g_scr[16], l1_scr[8];

  const int tid = threadIdx.x;
  const int lane = tid & 63;
  const int wid = tid >> 6;
  const int mh = wid & 1;   // m-half: 0 -> m0..3, 1 -> m4..7
  const int eh = wid >> 1;  // e-half

  // prologue: stage w (scatter-repack) + G into LDS
#pragma unroll
  for (int i = 0; i < 7; ++i) {
    const int idx = tid + i * 256;
    const float4 v = ((const float4*)w)[idx];
    const float vv[4] = {v.x, v.y, v.z, v.w};
#pragma unroll
    for (int k = 0; k < 4; ++k) {
      const int f = idx * 4 + k;
      const int e = f / 14;  // magic-mul
      const int c = f - e * 14;
      wp_s[(c >> 1) * 1024 + e * 2 + (c & 1)] = vv[k];
    }
  }
  if (tid < 196) G_s[tid] = wsf[NSLOTS + tid];

  float block_loss = 0.f;

  for (int s = 0; s < S_PER_BLOCK; ++s) {
    const int b = blockIdx.x * S_PER_BLOCK + s;
    const float* xrow = x + (size_t)b * (E_LEN * 8);

    __syncthreads();  // bar A: prologue ready / previous sample consumed
    if (tid < C_CLS) P_s[tid] = (y[b * C_CLS + tid] == 1) ? 1.f : 0.f;

    // ---- phase 1: each wave loads its (eh, mh) quarter of x exactly once ----
    float U[4][4];
#pragma unroll
    for (int j = 0; j < 4; ++j) {
      const int e = eh * 256 + j * 64 + lane;
      *(float4*)U[j] = *(const float4*)(xrow + e * 8 + mh * 4);
    }
    // per-e variance partials over this m-half
    float vs1[4], vs2[4];
#pragma unroll
    for (int j = 0; j < 4; ++j) {
      float s1 = U[j][0] + U[j][1] + U[j][2] + U[j][3];
      float s2 = U[j][0] * U[j][0];
      s2 = fmaf(U[j][1], U[j][1], s2);
      s2 = fmaf(U[j][2], U[j][2], s2);
      s2 = fmaf(U[j][3], U[j][3], s2);
      vs1[j] = s1;
      vs2[j] = s2;
    }
    if (mh == 1) {
#pragma unroll
      for (int j = 0; j < 4; ++j) {
        const int e = eh * 256 + j * 64 + lane;
        *(float2*)(var_s + e * 2) = make_float2(vs1[j], vs2[j]);
      }
    }
    float acc[14][4];
#pragma unroll
    for (int c = 0; c < 14; ++c)
#pragma unroll
      for (int m = 0; m < 4; ++m) acc[c][m] = 0.f;
#pragma unroll
    for (int j = 0; j < 4; ++j) {
      const int e = eh * 256 + j * 64 + lane;
      const float* wb = wp_s + e * 2;
#pragma unroll
      for (int cp = 0; cp < 7; ++cp) {
        const float2 w2 = *(const float2*)(wb + cp * 1024);
#pragma unroll
        for (int m = 0; m < 4; ++m) {
          acc[2 * cp][m]     = fmaf(U[j][m], w2.x, acc[2 * cp][m]);
          acc[2 * cp + 1][m] = fmaf(U[j][m], w2.y, acc[2 * cp + 1][m]);
        }
      }
    }
    // in-wave partial reduce (16 lanes -> 4 partials/row), stash to scratch
#pragma unroll
    for (int c = 0; c < 14; ++c)
#pragma unroll
      for (int m = 0; m < 4; ++m) acc[c][m] = sum4_16(acc[c][m]);
    if ((lane & 15) < 4) {
      const int part = eh * 16 + (lane >> 4) * 4 + (lane & 3);  // 0..31
#pragma unroll
      for (int c = 0; c < 14; ++c)
        *(float4*)(scr + c * 264 + part * 8 + mh * 4) =
            make_float4(acc[c][0], acc[c][1], acc[c][2], acc[c][3]);
    }
    __syncthreads();  // bar B

    // ---- phase 2a (mh=1 waves): finish dot reduction, max over m ----
    if (mh == 1) {
      const int r = eh * 64 + lane;  // 0..127
      const int craw = r >> 3;
      const int c = (craw > 13) ? 13 : craw;
      const int m = r & 7;
      float dv = 0.f;
#pragma unroll
      for (int p = 0; p < 32; ++p) dv += scr[c * 264 + p * 8 + m];
      dv = max8(dv);
      if ((r & 7) == 0 && craw < 14) dot_s[c] = dv;
    } else {
      // ---- phase 2b (mh=0 waves): finalize per-e variance -> l1 ----
      float l1 = 0.f;
#pragma unroll
      for (int j = 0; j < 4; ++j) {
        const int e = eh * 256 + j * 64 + lane;
        const float2 o = *(const float2*)(var_s + e * 2);
        const float s1 = vs1[j] + o.x;
        const float s2 = vs2[j] + o.y;
        const float sig = (s2 - s1 * s1 * 0.125f) * (1.f / 7.f);  // ddof=1
        l1 += fabsf(sig);
      }
      l1 = sum16(l1);
      if ((lane & 15) == 0) l1_scr[eh * 4 + (lane >> 4)] = l1;
    }
    __syncthreads();  // bar C

    // ---- phase 3: 196 (p,n) pairs -> softplus pair sum + masked Gram sum ----
    {
      const int tt = (tid < 196) ? tid : 0;
      const int p = tt / 14;
      const int n = tt - p * 14;
      const float act = (tid < 196) ? 1.f : 0.f;
      const float Pp = P_s[p];
      const float Pn = P_s[n];
      const float v = dot_s[n] - dot_s[p];
      float aP = act * Pp * (1.f - Pn) * softplus_f(v);
      float aG = act * Pp * Pn * G_s[tt];
      aP = sum16(aP);
      aG = sum16(aG);
      if ((lane & 15) == 0) {
        pair_scr[tid >> 4] = aP;
        g_scr[tid >> 4] = aG;
      }
    }
    __syncthreads();  // bar D

    // ---- phase 4: per-sample assembly ----
    if (tid == 0) {
      float S = 0.f, sumG = 0.f;
#pragma unroll
      for (int r2 = 0; r2 < 16; ++r2) { S += pair_scr[r2]; sumG += g_scr[r2]; }
      float l1e = 0.f;
#pragma unroll
      for (int r2 = 0; r2 < 8; ++r2) l1e += l1_scr[r2];
      float npos = 0.f;
      for (int c = 0; c < 14; ++c) npos += P_s[c];
      const float nneg = 14.f - npos;
      float base;
      if (nneg > 0.f) {
        base = S / npos;
      } else {  // reference edge case (unreachable with this setup)
        float t2 = 0.f;
        for (int c = 0; c < 14; ++c)
          if (P_s[c] > 0.5f) t2 += softplus_f(-dot_s[c]);
        base = t2 / npos;
      }
      // diversity via Gram identity: sum_e ss = sum_{c in P} G[c][c] - sumG/npos
      float sumW2 = 0.f;
      for (int c = 0; c < 14; ++c) sumW2 += P_s[c] * G_s[c * 14 + c];
      float tv = 0.f;
      if (npos > 1.5f) tv = (sumW2 - sumG / npos) / (npos - 1.f);
      // loss = 2*((1-beta)*(1+tv)*base + beta*l1), beta=0.3
      block_loss += 1.4f * (1.f + tv) * base + 0.6f * l1e;
    }
  }
  if (tid == 0) atomicAdd(&slots[blockIdx.x & (NSLOTS - 1)], block_loss);
}

// ---- finalize (1 wave): sum the 256 slots -> out[0] ----
__global__ void MID_LOSS_fin(const float* __restrict__ wsf,
                             float* __restrict__ out) {
  __shared__ float r[4];
  const int tid = threadIdx.x;  // 64 threads
  float s = wsf[tid] + wsf[tid + 64] + wsf[tid + 128] + wsf[tid + 192];
  s = sum16(s);
  if ((tid & 15) == 0) r[tid >> 4] = s;
  __syncthreads();
  if (tid == 0) out[0] = (r[0] + r[1] + r[2] + r[3]) * (1.f / (float)BATCH);
}

extern "C" void kernel_launch(void* const* d_in, const int* in_sizes, int n_in,
                              void* d_out, int out_size, void* d_ws, size_t ws_size,
                              hipStream_t stream) {
  const float* x = (const float*)d_in[0];
  const int* y = (const int*)d_in[1];
  const float* w = (const float*)d_in[2];
  float* out = (float*)d_out;
  float* wsf = (float*)d_ws;

  MID_LOSS_prep<<<1, 256, 0, stream>>>(w, wsf);
  MID_LOSS_main<<<BATCH / S_PER_BLOCK, 256, 0, stream>>>(x, y, w, wsf, wsf);
  MID_LOSS_fin<<<1, 64, 0, stream>>>(wsf, out);
}